// Round 7
// baseline (1950.341 us; speedup 1.0000x reference)
//
#include <hip/hip_runtime.h>
#include <hip/hip_bf16.h>
#include <math.h>

typedef unsigned short u16;
typedef __bf16 bf16x8_t __attribute__((ext_vector_type(8)));
typedef float  f32x4_t  __attribute__((ext_vector_type(4)));
typedef float  f32x8_t  __attribute__((ext_vector_type(8)));
typedef float  f32x16_t __attribute__((ext_vector_type(16)));
typedef u16    u16x4_t  __attribute__((ext_vector_type(4)));
typedef u16    u16x8_t  __attribute__((ext_vector_type(8)));

// ---------- helpers ----------
__device__ __forceinline__ u16 f2b(float f) {
  unsigned u = __builtin_bit_cast(unsigned, f);
  u += 0x7fffu + ((u >> 16) & 1u);      // RNE; inputs are finite
  return (u16)(u >> 16);
}
__device__ __forceinline__ float b2f(u16 h) {
  unsigned u = ((unsigned)h) << 16;
  return __builtin_bit_cast(float, u);
}
__device__ __forceinline__ float sigm_(float x) { return 1.0f / (1.0f + __expf(-x)); }
__device__ __forceinline__ float tanh_(float x) { return 1.0f - 2.0f / (__expf(2.0f * x) + 1.0f); }

__device__ __forceinline__ void gload16(const void* g, void* l) {
  __builtin_amdgcn_global_load_lds(
      (__attribute__((address_space(1))) void*)(g),
      (__attribute__((address_space(3))) void*)(l), 16, 0, 0);
}

// ==========================================================================
// Packed panel formats (k-plane = 8 consecutive k as 16B per row):
//  A panel: 128-row tiles [p 0..3][row 0..127][8 u16] = 4096 u16 (8 KB)
//           A1p[mb 0..127][kt 0..KT-1][4096]
//  B panel: 256-row tiles [p 0..3][row 0..255][8 u16] = 8192 u16 (16 KB)
//           W*tp[nb][kt][8192]
// Staging = contiguous 16B/thread wave loads, LDS image == packed tile ->
// conflict-free ds_read_b128 fragments (32 consecutive rows per 32-lane half).
// ==========================================================================

// ---------- pack fp32 activations [B,C] -> packed A panel (col offset c0) ----------
// grid (128, C/64), block 256: row = t&127, ktl = by*2 + (t>>7)
__global__ void cvt_act_kernel(const float* __restrict__ src, u16* __restrict__ dst,
                               int C, int KT, int c0) {
  int mbg = blockIdx.x, t = threadIdx.x;
  int row = t & 127;
  int ktl = blockIdx.y * 2 + (t >> 7);
  const float* s = src + (long)(mbg * 128 + row) * C + ktl * 32;
  u16* d = dst + ((long)(mbg * KT + (c0 >> 5) + ktl)) * 4096 + row * 8;
#pragma unroll
  for (int p = 0; p < 4; ++p) {
    f32x8_t v = *(const f32x8_t*)(s + p * 8);
    u16x8_t o;
#pragma unroll
    for (int r = 0; r < 8; ++r) o[r] = f2b(v[r]);
    *(u16x8_t*)(d + p * 1024) = o;
  }
}

// ---------- pack fp32 weight [K,N] (transposed) -> packed B panel ----------
__global__ void cvt_wt_kernel(const float* __restrict__ src, u16* __restrict__ dst,
                              int N, int KT, int n0, int k0) {
  int bx = blockIdx.x, by = blockIdx.y, t = threadIdx.x;
  int n = bx * 256 + t;
  int nb_g = (n0 >> 8) + bx;
  int ktg = (k0 >> 5) + by;
  float tmp[32];
#pragma unroll
  for (int kk = 0; kk < 32; ++kk)
    tmp[kk] = src[(long)(by * 32 + kk) * N + n];
  u16* d = dst + ((long)(nb_g * KT + ktg)) * 8192 + t * 8;
#pragma unroll
  for (int p = 0; p < 4; ++p) {
    u16x8_t o;
#pragma unroll
    for (int r = 0; r < 8; ++r) o[r] = f2b(tmp[p * 8 + r]);
    *(u16x8_t*)(d + p * 2048) = o;
  }
}

// ==========================================================================
// 128x256 bf16 GEMM, 32x32x16 MFMA, 8 waves (2M x 4N), wave tile 64x64.
// acc = 2x2 f32x16 (64 VGPR) -> fits 4 waves/SIMD; LDS 3-slot ring x 24KB
// = 72 KB -> 2 blocks/CU. Cross-block skew provides DS<->MFMA overlap.
// R4-proven counted-vmcnt ring: stage t+2 while computing t; boundary
// vmcnt(3) certifies tile t+1 resident with t+2's 3 loads in flight.
// Operands swapped (W as A-op): lane's acc = row l31(+mm*32),
// cols 4*hl + (reg&3) + 8*(reg>>2) (+nn*32)  [verified R6 pass].
// MODE 0: A1p[128mb x 160kt] x W1tp[32nb x 160kt] -> G1 [16384,8192]
//         NT per nb: nb<16 -> 160, nb<28 -> 96, else 64 (segmented K)
// MODE 1: A2p[128mb x 128kt] x W2tp[8nb x 128kt]  -> G2 [16384,2048], NT=64
// ==========================================================================
template <int MODE>
__global__ __launch_bounds__(512, 4) void gemm128_kernel(
    const u16* __restrict__ A, const u16* __restrict__ Bt, u16* __restrict__ Cout) {
  constexpr int KTF  = (MODE == 0) ? 160 : 128;
  constexpr int NCOL = (MODE == 0) ? 8192 : 2048;
  constexpr int NBN  = NCOL / 256;
  constexpr int SLOT = 12288;   // u16: A tile 4096 + B tile 8192

  __shared__ u16 lds[3 * SLOT];  // 72 KiB

  // XCD-bijective swizzle (grid % 8 == 0 in both modes)
  int bid = blockIdx.x;
  int cpx = gridDim.x >> 3;
  bid = (bid & 7) * cpx + (bid >> 3);

  int mb = bid / NBN, nb = bid % NBN;
  int m0 = mb * 128, n0 = nb * 256;

  int kt0, NT;  // K32-tile units
  if (MODE == 0) { kt0 = 0; NT = (nb < 16) ? 160 : ((nb < 28) ? 96 : 64); }
  else           { kt0 = (nb < 4) ? 0 : 64; NT = 64; }

  const int tid  = threadIdx.x;
  const int lane = tid & 63;
  const int wid  = tid >> 6;
  const int wr   = wid >> 2;       // 0..1  (wave row: 64 output rows)
  const int wc   = wid & 3;        // 0..3  (wave col: 64 output cols)
  const int l31  = lane & 31;
  const int hl   = lane >> 5;

  // staging: thread copies 16B of A-tile + 2x16B of B-tile per iter
  const int dstg = tid * 8;  // u16
  const u16* pA = A  + ((long)(mb * KTF + kt0)) * 4096 + dstg;
  const u16* pB = Bt + ((long)(nb * KTF + kt0)) * 8192 + dstg;

#define STG(s, tt) do { \
    gload16(pA + (long)(tt) * 4096,        &lds[(s) * SLOT + dstg]); \
    gload16(pB + (long)(tt) * 8192,        &lds[(s) * SLOT + 4096 + dstg]); \
    gload16(pB + (long)(tt) * 8192 + 4096, &lds[(s) * SLOT + 8192 + dstg]); } while (0)

  // fragment bases (u16 units): A plane stride 1024, B plane stride 2048
  const int xb = (wr * 64 + l31) * 8;   // + mm*256, + (2ks+hl)*1024
  const int wb = (wc * 64 + l31) * 8;   // + nn*256, + (2ks+hl)*2048, base 4096

  f32x16_t acc[2][2];
#pragma unroll
  for (int m = 0; m < 2; ++m)
#pragma unroll
    for (int n = 0; n < 2; ++n)
#pragma unroll
      for (int r = 0; r < 16; ++r) acc[m][n][r] = 0.f;

  // ---- prologue: stage tiles 0,1 into slots 0,1 ----
  STG(0, 0); STG(1, 1);
  asm volatile("s_waitcnt vmcnt(3)" ::: "memory");   // tile 0 resident
  __builtin_amdgcn_s_barrier();

  int slot = 0, s2 = 2;
  for (int t = 0; t < NT; ++t) {
    const u16* sb = &lds[slot * SLOT];
    const bool pre = (t + 2 < NT);
    if (pre) STG(s2, t + 2);

#pragma unroll
    for (int ks = 0; ks < 2; ++ks) {
      const u16* ta = sb + (2 * ks + hl) * 1024;
      const u16* tb = sb + 4096 + (2 * ks + hl) * 2048;
      bf16x8_t x0 = *(const bf16x8_t*)(ta + xb);
      bf16x8_t x1 = *(const bf16x8_t*)(ta + xb + 256);
      bf16x8_t w0 = *(const bf16x8_t*)(tb + wb);
      bf16x8_t w1 = *(const bf16x8_t*)(tb + wb + 256);
      __builtin_amdgcn_s_setprio(1);
      acc[0][0] = __builtin_amdgcn_mfma_f32_32x32x16_bf16(w0, x0, acc[0][0], 0, 0, 0);
      acc[0][1] = __builtin_amdgcn_mfma_f32_32x32x16_bf16(w1, x0, acc[0][1], 0, 0, 0);
      acc[1][0] = __builtin_amdgcn_mfma_f32_32x32x16_bf16(w0, x1, acc[1][0], 0, 0, 0);
      acc[1][1] = __builtin_amdgcn_mfma_f32_32x32x16_bf16(w1, x1, acc[1][1], 0, 0, 0);
      __builtin_amdgcn_s_setprio(0);
    }

    if (pre) asm volatile("s_waitcnt vmcnt(3)" ::: "memory");  // t+1 resident, t+2 in flight
    else     asm volatile("s_waitcnt vmcnt(0)" ::: "memory");  // epilogue drain
    __builtin_amdgcn_s_barrier();

    slot = (slot == 2) ? 0 : slot + 1;
    s2   = (s2   == 2) ? 0 : s2   + 1;
  }
#undef STG

  // ---- epilogue: row = l31 (+mm*32), cols = nn*32 + g*8 + 4*hl + 0..3 ----
  const long rowg = (long)(m0 + wr * 64 + l31);
  const int  colg = n0 + wc * 64 + 4 * hl;
#pragma unroll
  for (int mm = 0; mm < 2; ++mm) {
    long rb = (rowg + mm * 32) * (long)NCOL;
#pragma unroll
    for (int nn = 0; nn < 2; ++nn) {
#pragma unroll
      for (int g = 0; g < 4; ++g) {
        u16x4_t o;
#pragma unroll
        for (int r = 0; r < 4; ++r) o[r] = f2b(acc[mm][nn][g * 4 + r]);
        *(u16x4_t*)&Cout[rb + colg + nn * 32 + g * 8] = o;
      }
    }
  }
}

// ---------- pass2: gates -> c_new (fp32), A2 packed = [bf16(c_new) | bf16(tanh(c_new))] ----------
// grid (128, 32), block 256: row = t&127, jg = by*2 + (t>>7)
__global__ void pass2_kernel(const u16* __restrict__ G1, const float* __restrict__ c_t,
                             const float* __restrict__ bias_i, const float* __restrict__ bias_f,
                             const float* __restrict__ bias_c,
                             float* __restrict__ c_new_out, u16* __restrict__ A2p) {
  int mb = blockIdx.x, t = threadIdx.x;
  int row = t & 127;
  int jg = blockIdx.y * 2 + (t >> 7);   // 0..63
  int b = mb * 128 + row;
  int j0 = jg * 32;
  const u16* grow = G1 + (long)b * 8192 + j0;
  const float* cp_p = c_t + (long)b * 2048 + j0;
  float* co_p = c_new_out + (long)b * 2048 + j0;
  // A2p[mb 0..127][kt 0..127][4096]: c part kt=jg, r part kt=64+jg
  u16* dc = A2p + ((long)(mb * 128 + jg)) * 4096 + row * 8;
  u16* dr = dc + (long)64 * 4096;

#pragma unroll
  for (int q = 0; q < 4; ++q) {
    u16x8_t ip = *(const u16x8_t*)(grow + q * 8);
    u16x8_t fp = *(const u16x8_t*)(grow + 2048 + q * 8);
    u16x8_t gp = *(const u16x8_t*)(grow + 4096 + q * 8);
    f32x8_t cp = *(const f32x8_t*)(cp_p + q * 8);
    f32x8_t bi = *(const f32x8_t*)(bias_i + j0 + q * 8);
    f32x8_t bf = *(const f32x8_t*)(bias_f + j0 + q * 8);
    f32x8_t bc = *(const f32x8_t*)(bias_c + j0 + q * 8);
    f32x8_t cn;
    u16x8_t cb, rb;
#pragma unroll
    for (int r = 0; r < 8; ++r) {
      float ig = sigm_(b2f(ip[r]) + bi[r]);
      float fg = sigm_(b2f(fp[r]) + bf[r]);
      float g  = tanh_(b2f(gp[r]) + bc[r]);
      float c  = fg * cp[r] + ig * g;
      cn[r] = c;
      cb[r] = f2b(c);
      rb[r] = f2b(tanh_(c));
    }
    *(f32x8_t*)(co_p + q * 8) = cn;
    *(u16x8_t*)(dc + q * 1024) = cb;
    *(u16x8_t*)(dr + q * 1024) = rb;
  }
}

// ---------- pass3: h_new = sigmoid(og_pre + c@Woc + bias_o) * (m_t + xr) ----------
__global__ void pass3_kernel(const u16* __restrict__ G1, const u16* __restrict__ G2,
                             const float* __restrict__ bias_o, float* __restrict__ h_out) {
  long i = (long)blockIdx.x * blockDim.x + threadIdx.x;
  long e = i * 8;
  int b = (int)(e >> 10);
  int j = (int)(e & 1023);
  const u16* row1 = G1 + (long)b * 8192;
  const u16* row2 = G2 + (long)b * 2048;
  u16x8_t ogp = *(const u16x8_t*)(row1 + 6144 + j);
  u16x8_t xrp = *(const u16x8_t*)(row1 + 7168 + j);
  u16x8_t ocg = *(const u16x8_t*)(row2 + j);
  u16x8_t mt  = *(const u16x8_t*)(row2 + 1024 + j);
  f32x8_t bo  = *(const f32x8_t*)(bias_o + j);
  f32x8_t h;
#pragma unroll
  for (int r = 0; r < 8; ++r) {
    float og = sigm_(b2f(ogp[r]) + b2f(ocg[r]) + bo[r]);
    h[r] = og * (b2f(mt[r]) + b2f(xrp[r]));
  }
  *(f32x8_t*)(h_out + (long)b * 1024 + j) = h;
}

// ---------- launch ----------
extern "C" void kernel_launch(void* const* d_in, const int* in_sizes, int n_in,
                              void* d_out, int out_size, void* d_ws, size_t ws_size,
                              hipStream_t stream) {
  const float* x_t      = (const float*)d_in[0];
  const float* h_t      = (const float*)d_in[1];
  const float* c_t      = (const float*)d_in[2];
  const float* w_if_x   = (const float*)d_in[3];
  const float* w_if_h   = (const float*)d_in[4];
  const float* w_if_c   = (const float*)d_in[5];
  const float* bias_i   = (const float*)d_in[6];
  const float* bias_f   = (const float*)d_in[7];
  const float* w_c_x    = (const float*)d_in[8];
  const float* w_c_h    = (const float*)d_in[9];
  const float* bias_c   = (const float*)d_in[10];
  const float* w_o_x    = (const float*)d_in[11];
  const float* w_o_h    = (const float*)d_in[12];
  const float* w_o_c    = (const float*)d_in[13];
  const float* bias_o   = (const float*)d_in[14];
  const float* w_r_proj = (const float*)d_in[15];
  const float* w_r_x    = (const float*)d_in[16];

  char* ws = (char*)d_ws;
  // layout (512 MiB):
  //   A1p  [128][160][4096]u16 @ 0        (160 MiB)
  //   W1tp [32][160][8192]u16  @ 160 MiB  ( 80 MiB)
  //   G1   [16384,8192] bf16   @ 240 MiB  (256 MiB)
  //   W2tp [8][128][8192]u16   @ 496 MiB  ( 16 MiB)
  //   A2p  [128][128][4096]u16 @ 0        (aliases A1p, dead after GEMM1)
  //   G2   [16384,2048] bf16   @ 160 MiB  (aliases W1tp, dead after GEMM1)
  u16* A1p  = (u16*)(ws);
  u16* W1tp = (u16*)(ws + 167772160L);
  u16* G1   = (u16*)(ws + 251658240L);
  u16* W2tp = (u16*)(ws + 520093696L);
  u16* A2p  = (u16*)(ws);
  u16* G2   = (u16*)(ws + 167772160L);

  float* h_out = (float*)d_out;
  float* c_out = h_out + 16384L * 1024L;

  // --- stage 0: pack activations (A1 panel k-map: x 0..63, h 64..95, c 96..159) ---
  cvt_act_kernel<<<dim3(128, 32), 256, 0, stream>>>(x_t, A1p, 2048, 160, 0);
  cvt_act_kernel<<<dim3(128, 16), 256, 0, stream>>>(h_t, A1p, 1024, 160, 2048);
  cvt_act_kernel<<<dim3(128, 32), 256, 0, stream>>>(c_t, A1p, 2048, 160, 3072);

  // --- pack weights (transposed) ---
  cvt_wt_kernel<<<dim3(16, 64), 256, 0, stream>>>(w_if_x,   W1tp, 4096, 160, 0,    0);
  cvt_wt_kernel<<<dim3(16, 32), 256, 0, stream>>>(w_if_h,   W1tp, 4096, 160, 0,    2048);
  cvt_wt_kernel<<<dim3(16, 64), 256, 0, stream>>>(w_if_c,   W1tp, 4096, 160, 0,    3072);
  cvt_wt_kernel<<<dim3(8,  64), 256, 0, stream>>>(w_c_x,    W1tp, 2048, 160, 4096, 0);
  cvt_wt_kernel<<<dim3(8,  32), 256, 0, stream>>>(w_c_h,    W1tp, 2048, 160, 4096, 2048);
  cvt_wt_kernel<<<dim3(4,  64), 256, 0, stream>>>(w_o_x,    W1tp, 1024, 160, 6144, 0);
  cvt_wt_kernel<<<dim3(4,  32), 256, 0, stream>>>(w_o_h,    W1tp, 1024, 160, 6144, 2048);
  cvt_wt_kernel<<<dim3(4,  64), 256, 0, stream>>>(w_r_x,    W1tp, 1024, 160, 7168, 0);
  cvt_wt_kernel<<<dim3(4,  64), 256, 0, stream>>>(w_o_c,    W2tp, 1024, 128, 0,    0);
  cvt_wt_kernel<<<dim3(4,  64), 256, 0, stream>>>(w_r_proj, W2tp, 1024, 128, 1024, 2048);

  // --- stage 1: big fused GEMM -> all pre-activations ---
  gemm128_kernel<0><<<4096, 512, 0, stream>>>(A1p, W1tp, G1);

  // --- stage 2: elementwise gates -> c_new + packed A2 ---
  pass2_kernel<<<dim3(128, 32), 256, 0, stream>>>(G1, c_t, bias_i, bias_f, bias_c, c_out, A2p);

  // --- stage 3: [c_new|r_t] GEMM -> og peephole + m_t ---
  gemm128_kernel<1><<<1024, 512, 0, stream>>>(A2p, W2tp, G2);

  // --- stage 4: h_new ---
  pass3_kernel<<<8192, 256, 0, stream>>>(G1, G2, bias_o, h_out);
}

// Round 8
// 1723.271 us; speedup vs baseline: 1.1318x; 1.1318x over previous
//
#include <hip/hip_runtime.h>
#include <hip/hip_bf16.h>
#include <math.h>

typedef unsigned short u16;
typedef __bf16 bf16x8_t __attribute__((ext_vector_type(8)));
typedef float  f32x4_t  __attribute__((ext_vector_type(4)));
typedef float  f32x8_t  __attribute__((ext_vector_type(8)));
typedef float  f32x16_t __attribute__((ext_vector_type(16)));
typedef u16    u16x4_t  __attribute__((ext_vector_type(4)));
typedef u16    u16x8_t  __attribute__((ext_vector_type(8)));

// ---------- helpers ----------
__device__ __forceinline__ u16 f2b(float f) {
  unsigned u = __builtin_bit_cast(unsigned, f);
  u += 0x7fffu + ((u >> 16) & 1u);      // RNE; inputs are finite
  return (u16)(u >> 16);
}
__device__ __forceinline__ float b2f(u16 h) {
  unsigned u = ((unsigned)h) << 16;
  return __builtin_bit_cast(float, u);
}
__device__ __forceinline__ float sigm_(float x) { return 1.0f / (1.0f + __expf(-x)); }
__device__ __forceinline__ float tanh_(float x) { return 1.0f - 2.0f / (__expf(2.0f * x) + 1.0f); }

__device__ __forceinline__ void gload16(const void* g, void* l) {
  __builtin_amdgcn_global_load_lds(
      (__attribute__((address_space(1))) void*)(g),
      (__attribute__((address_space(3))) void*)(l), 16, 0, 0);
}

// ==========================================================================
// Packed panel format (256-row tiles): [k-plane p=0..3][row 0..255][8 u16]
// = 8192 u16 (16 KB) per 256x32 tile; panel = [blk][kt][8192], stride KT.
// ==========================================================================

// ---------- pack fp32 activations [B,C] -> packed bf16 panel (col offset c0) ----------
__global__ void cvt_act_kernel(const float* __restrict__ src, u16* __restrict__ dst,
                               int C, int KT, int c0) {
  int mb = blockIdx.x, ktl = blockIdx.y, t = threadIdx.x;
  int ktg = (c0 >> 5) + ktl;
  const float* s = src + (long)(mb * 256 + t) * C + ktl * 32;
  u16* d = dst + ((long)(mb * KT + ktg)) * 8192 + t * 8;
#pragma unroll
  for (int p = 0; p < 4; ++p) {
    f32x8_t v = *(const f32x8_t*)(s + p * 8);
    u16x8_t o;
#pragma unroll
    for (int r = 0; r < 8; ++r) o[r] = f2b(v[r]);
    *(u16x8_t*)(d + p * 2048) = o;
  }
}

// ---------- pack fp32 weight [K,N] (transposed) -> packed bf16 panel ----------
__global__ void cvt_wt_kernel(const float* __restrict__ src, u16* __restrict__ dst,
                              int N, int KT, int n0, int k0) {
  int bx = blockIdx.x, by = blockIdx.y, t = threadIdx.x;
  int n = bx * 256 + t;
  int nb_g = (n0 >> 8) + bx;
  int ktg = (k0 >> 5) + by;
  float tmp[32];
#pragma unroll
  for (int kk = 0; kk < 32; ++kk)
    tmp[kk] = src[(long)(by * 32 + kk) * N + n];
  u16* d = dst + ((long)(nb_g * KT + ktg)) * 8192 + t * 8;
#pragma unroll
  for (int p = 0; p < 4; ++p) {
    u16x8_t o;
#pragma unroll
    for (int r = 0; r < 8; ++r) o[r] = f2b(tmp[p * 8 + r]);
    *(u16x8_t*)(d + p * 2048) = o;
  }
}

// ==========================================================================
// 256x256 bf16 GEMM, 32x32x16 MFMA, 8 waves (2M x 4N), wave tile 128x64.
// A: LDS 3-slot ring (16KB/tile, global_load_lds, stage t+2, vmcnt(6) edge).
// B: DIRECT GLOBAL->VGPR per wave (4 x 16B loads/tile, prefetched 1 tile
//    ahead, compiler-scoreboarded counted vmcnt -> no barrier coupling).
// One barrier per K32 tile. acc[4][2] f32x16 = 128 VGPR.
// Operands swapped (W as MFMA A-op): out row = lane&31 (+mm*32),
// cols = nn*32 + g*8 + 4*(lane>>5) + r   [verified R6/R7].
// MODE 0: A1p[64mb x 160kt] x W1tp[32nb x 160kt] -> G1 [16384,8192]
//         NT per nb: nb<16 -> 160, nb<28 -> 96, else 64 (segmented K)
// MODE 1: A2p[64mb x 128kt] x W2tp[8nb x 128kt]  -> G2 [16384,2048], NT=64
// ==========================================================================
template <int MODE>
__global__ __launch_bounds__(512, 2) void gemm256_kernel(
    const u16* __restrict__ A, const u16* __restrict__ Bt, u16* __restrict__ Cout) {
  constexpr int KTF  = (MODE == 0) ? 160 : 128;
  constexpr int NCOL = (MODE == 0) ? 8192 : 2048;
  constexpr int NBN  = NCOL / 256;

  __shared__ u16 lds[3 * 8192];  // 48 KiB: 3-slot A ring

  // XCD-bijective swizzle (grid % 8 == 0 in both modes)
  int bid = blockIdx.x;
  int cpx = gridDim.x >> 3;
  bid = (bid & 7) * cpx + (bid >> 3);

  int mb = bid / NBN, nb = bid % NBN;
  int m0 = mb * 256, n0 = nb * 256;

  int kt0, NT;  // K32-tile units
  if (MODE == 0) { kt0 = 0; NT = (nb < 16) ? 160 : ((nb < 28) ? 96 : 64); }
  else           { kt0 = (nb < 4) ? 0 : 64; NT = 64; }

  const int tid  = threadIdx.x;
  const int lane = tid & 63;
  const int wid  = tid >> 6;
  const int wr   = wid >> 2;       // 0..1  (wave row: 128 output rows)
  const int wc   = wid & 3;        // 0..3  (wave col: 64 output cols)
  const int l31  = lane & 31;
  const int hl   = lane >> 5;

  // A staging (LDS): thread copies 2x16B per tile; LDS image == packed tile
  const int dstg = tid * 8;  // u16
  const u16* pA = A + ((long)(mb * KTF + kt0)) * 8192 + dstg;

  // B per-thread fragment base: frag(nn,kk) of tile tt at
  //   pBr + tt*8192 + kk*4096 + nn*256
  const u16* pBr = Bt + ((long)(nb * KTF + kt0)) * 8192
                 + hl * 2048 + (wc * 64 + l31) * 8;

  f32x16_t acc[4][2];
#pragma unroll
  for (int m = 0; m < 4; ++m)
#pragma unroll
    for (int n = 0; n < 2; ++n)
#pragma unroll
      for (int r = 0; r < 16; ++r) acc[m][n][r] = 0.f;

  bf16x8_t bA[4], bB[4];

  // ---- prologue: stage A tiles 0,1 (slots 0,1); load B tile 0 to regs ----
  gload16(pA,        &lds[dstg]);
  gload16(pA + 4096, &lds[4096 + dstg]);
  gload16(pA + 8192,        &lds[8192 + dstg]);
  gload16(pA + 8192 + 4096, &lds[8192 + 4096 + dstg]);
  bA[0] = *(const bf16x8_t*)(pBr);
  bA[1] = *(const bf16x8_t*)(pBr + 256);
  bA[2] = *(const bf16x8_t*)(pBr + 4096);
  bA[3] = *(const bf16x8_t*)(pBr + 4096 + 256);
  asm volatile("s_waitcnt vmcnt(0)" ::: "memory");
  __builtin_amdgcn_s_barrier();

  int _slot = 0, _s2 = 2;

#define ITER(TT, CUR, NXT) do { \
    const int _t = (TT); \
    const u16* _sb = &lds[_slot * 8192]; \
    const bool _p1 = (_t + 1 < NT), _p2 = (_t + 2 < NT); \
    if (_p1) { \
      const u16* _pb = pBr + (long)(_t + 1) * 8192; \
      NXT[0] = *(const bf16x8_t*)(_pb); \
      NXT[1] = *(const bf16x8_t*)(_pb + 256); \
      NXT[2] = *(const bf16x8_t*)(_pb + 4096); \
      NXT[3] = *(const bf16x8_t*)(_pb + 4096 + 256); \
    } \
    if (_p2) { \
      gload16(pA + (long)(_t + 2) * 8192,        &lds[_s2 * 8192 + dstg]); \
      gload16(pA + (long)(_t + 2) * 8192 + 4096, &lds[_s2 * 8192 + 4096 + dstg]); \
    } \
    bf16x8_t _a0, _a1, _a2, _a3; \
    _a0 = *(const bf16x8_t*)(_sb + hl * 2048 + (wr * 128 + l31) * 8); \
    _a1 = *(const bf16x8_t*)(_sb + hl * 2048 + (wr * 128 + 32 + l31) * 8); \
    _a2 = *(const bf16x8_t*)(_sb + hl * 2048 + (wr * 128 + 64 + l31) * 8); \
    _a3 = *(const bf16x8_t*)(_sb + hl * 2048 + (wr * 128 + 96 + l31) * 8); \
    __builtin_amdgcn_s_setprio(1); \
    acc[0][0] = __builtin_amdgcn_mfma_f32_32x32x16_bf16(CUR[0], _a0, acc[0][0], 0, 0, 0); \
    acc[0][1] = __builtin_amdgcn_mfma_f32_32x32x16_bf16(CUR[1], _a0, acc[0][1], 0, 0, 0); \
    acc[1][0] = __builtin_amdgcn_mfma_f32_32x32x16_bf16(CUR[0], _a1, acc[1][0], 0, 0, 0); \
    acc[1][1] = __builtin_amdgcn_mfma_f32_32x32x16_bf16(CUR[1], _a1, acc[1][1], 0, 0, 0); \
    acc[2][0] = __builtin_amdgcn_mfma_f32_32x32x16_bf16(CUR[0], _a2, acc[2][0], 0, 0, 0); \
    acc[2][1] = __builtin_amdgcn_mfma_f32_32x32x16_bf16(CUR[1], _a2, acc[2][1], 0, 0, 0); \
    acc[3][0] = __builtin_amdgcn_mfma_f32_32x32x16_bf16(CUR[0], _a3, acc[3][0], 0, 0, 0); \
    acc[3][1] = __builtin_amdgcn_mfma_f32_32x32x16_bf16(CUR[1], _a3, acc[3][1], 0, 0, 0); \
    _a0 = *(const bf16x8_t*)(_sb + (2 + hl) * 2048 + (wr * 128 + l31) * 8); \
    _a1 = *(const bf16x8_t*)(_sb + (2 + hl) * 2048 + (wr * 128 + 32 + l31) * 8); \
    _a2 = *(const bf16x8_t*)(_sb + (2 + hl) * 2048 + (wr * 128 + 64 + l31) * 8); \
    _a3 = *(const bf16x8_t*)(_sb + (2 + hl) * 2048 + (wr * 128 + 96 + l31) * 8); \
    acc[0][0] = __builtin_amdgcn_mfma_f32_32x32x16_bf16(CUR[2], _a0, acc[0][0], 0, 0, 0); \
    acc[0][1] = __builtin_amdgcn_mfma_f32_32x32x16_bf16(CUR[3], _a0, acc[0][1], 0, 0, 0); \
    acc[1][0] = __builtin_amdgcn_mfma_f32_32x32x16_bf16(CUR[2], _a1, acc[1][0], 0, 0, 0); \
    acc[1][1] = __builtin_amdgcn_mfma_f32_32x32x16_bf16(CUR[3], _a1, acc[1][1], 0, 0, 0); \
    acc[2][0] = __builtin_amdgcn_mfma_f32_32x32x16_bf16(CUR[2], _a2, acc[2][0], 0, 0, 0); \
    acc[2][1] = __builtin_amdgcn_mfma_f32_32x32x16_bf16(CUR[3], _a2, acc[2][1], 0, 0, 0); \
    acc[3][0] = __builtin_amdgcn_mfma_f32_32x32x16_bf16(CUR[2], _a3, acc[3][0], 0, 0, 0); \
    acc[3][1] = __builtin_amdgcn_mfma_f32_32x32x16_bf16(CUR[3], _a3, acc[3][1], 0, 0, 0); \
    __builtin_amdgcn_s_setprio(0); \
    if (_p2)      asm volatile("s_waitcnt vmcnt(6)" ::: "memory"); \
    else if (_p1) asm volatile("s_waitcnt vmcnt(4)" ::: "memory"); \
    else          asm volatile("s_waitcnt vmcnt(0)" ::: "memory"); \
    __builtin_amdgcn_s_barrier(); \
    _slot = (_slot == 2) ? 0 : _slot + 1; \
    _s2   = (_s2   == 2) ? 0 : _s2   + 1; \
  } while (0)

  for (int t = 0; t < NT; t += 2) {   // NT is even in all modes
    ITER(t,     bA, bB);
    ITER(t + 1, bB, bA);
  }
#undef ITER

  // ---- epilogue: row = l31 (+mm*32), cols = nn*32 + g*8 + 4*hl + 0..3 ----
  const long rowg = (long)(m0 + wr * 128 + l31);
  const int  colg = n0 + wc * 64 + 4 * hl;
#pragma unroll
  for (int mm = 0; mm < 4; ++mm) {
    long rb = (rowg + mm * 32) * (long)NCOL;
#pragma unroll
    for (int nn = 0; nn < 2; ++nn) {
#pragma unroll
      for (int g = 0; g < 4; ++g) {
        u16x4_t o;
#pragma unroll
        for (int r = 0; r < 4; ++r) o[r] = f2b(acc[mm][nn][g * 4 + r]);
        *(u16x4_t*)&Cout[rb + colg + nn * 32 + g * 8] = o;
      }
    }
  }
}

// ---------- pass2: gates -> c_new (fp32), A2 packed = [bf16(c_new) | bf16(tanh(c_new))] ----------
__global__ void pass2_kernel(const u16* __restrict__ G1, const float* __restrict__ c_t,
                             const float* __restrict__ bias_i, const float* __restrict__ bias_f,
                             const float* __restrict__ bias_c,
                             float* __restrict__ c_new_out, u16* __restrict__ A2p) {
  int mb = blockIdx.x, jg = blockIdx.y, t = threadIdx.x;
  int b = mb * 256 + t;
  int j0 = jg * 32;
  const u16* row = G1 + (long)b * 8192 + j0;
  const float* cp_p = c_t + (long)b * 2048 + j0;
  float* co_p = c_new_out + (long)b * 2048 + j0;
  u16* dc = A2p + ((long)(mb * 128 + jg)) * 8192 + t * 8;
  u16* dr = dc + (long)64 * 8192;

#pragma unroll
  for (int q = 0; q < 4; ++q) {
    u16x8_t ip = *(const u16x8_t*)(row + q * 8);
    u16x8_t fp = *(const u16x8_t*)(row + 2048 + q * 8);
    u16x8_t gp = *(const u16x8_t*)(row + 4096 + q * 8);
    f32x8_t cp = *(const f32x8_t*)(cp_p + q * 8);
    f32x8_t bi = *(const f32x8_t*)(bias_i + j0 + q * 8);
    f32x8_t bf = *(const f32x8_t*)(bias_f + j0 + q * 8);
    f32x8_t bc = *(const f32x8_t*)(bias_c + j0 + q * 8);
    f32x8_t cn;
    u16x8_t cb, rb;
#pragma unroll
    for (int r = 0; r < 8; ++r) {
      float ig = sigm_(b2f(ip[r]) + bi[r]);
      float fg = sigm_(b2f(fp[r]) + bf[r]);
      float g  = tanh_(b2f(gp[r]) + bc[r]);
      float c  = fg * cp[r] + ig * g;
      cn[r] = c;
      cb[r] = f2b(c);
      rb[r] = f2b(tanh_(c));
    }
    *(f32x8_t*)(co_p + q * 8) = cn;
    *(u16x8_t*)(dc + q * 2048) = cb;
    *(u16x8_t*)(dr + q * 2048) = rb;
  }
}

// ---------- pass3: h_new = sigmoid(og_pre + c@Woc + bias_o) * (m_t + xr) ----------
__global__ void pass3_kernel(const u16* __restrict__ G1, const u16* __restrict__ G2,
                             const float* __restrict__ bias_o, float* __restrict__ h_out) {
  long i = (long)blockIdx.x * blockDim.x + threadIdx.x;
  long e = i * 8;
  int b = (int)(e >> 10);
  int j = (int)(e & 1023);
  const u16* row1 = G1 + (long)b * 8192;
  const u16* row2 = G2 + (long)b * 2048;
  u16x8_t ogp = *(const u16x8_t*)(row1 + 6144 + j);
  u16x8_t xrp = *(const u16x8_t*)(row1 + 7168 + j);
  u16x8_t ocg = *(const u16x8_t*)(row2 + j);
  u16x8_t mt  = *(const u16x8_t*)(row2 + 1024 + j);
  f32x8_t bo  = *(const f32x8_t*)(bias_o + j);
  f32x8_t h;
#pragma unroll
  for (int r = 0; r < 8; ++r) {
    float og = sigm_(b2f(ogp[r]) + b2f(ocg[r]) + bo[r]);
    h[r] = og * (b2f(mt[r]) + b2f(xrp[r]));
  }
  *(f32x8_t*)(h_out + (long)b * 1024 + j) = h;
}

// ---------- launch ----------
extern "C" void kernel_launch(void* const* d_in, const int* in_sizes, int n_in,
                              void* d_out, int out_size, void* d_ws, size_t ws_size,
                              hipStream_t stream) {
  const float* x_t      = (const float*)d_in[0];
  const float* h_t      = (const float*)d_in[1];
  const float* c_t      = (const float*)d_in[2];
  const float* w_if_x   = (const float*)d_in[3];
  const float* w_if_h   = (const float*)d_in[4];
  const float* w_if_c   = (const float*)d_in[5];
  const float* bias_i   = (const float*)d_in[6];
  const float* bias_f   = (const float*)d_in[7];
  const float* w_c_x    = (const float*)d_in[8];
  const float* w_c_h    = (const float*)d_in[9];
  const float* bias_c   = (const float*)d_in[10];
  const float* w_o_x    = (const float*)d_in[11];
  const float* w_o_h    = (const float*)d_in[12];
  const float* w_o_c    = (const float*)d_in[13];
  const float* bias_o   = (const float*)d_in[14];
  const float* w_r_proj = (const float*)d_in[15];
  const float* w_r_x    = (const float*)d_in[16];

  char* ws = (char*)d_ws;
  u16* A1p  = (u16*)(ws);
  u16* W1tp = (u16*)(ws + 167772160L);
  u16* G1   = (u16*)(ws + 251658240L);
  u16* W2tp = (u16*)(ws + 520093696L);
  u16* A2p  = (u16*)(ws);               // aliases A1p (dead after GEMM1)
  u16* G2   = (u16*)(ws + 167772160L);  // aliases W1tp (dead after GEMM1)

  float* h_out = (float*)d_out;
  float* c_out = h_out + 16384L * 1024L;

  // --- stage 0: pack activations (A1 panel k-map: x 0..63, h 64..95, c 96..159) ---
  cvt_act_kernel<<<dim3(64, 64), 256, 0, stream>>>(x_t, A1p, 2048, 160, 0);
  cvt_act_kernel<<<dim3(64, 32), 256, 0, stream>>>(h_t, A1p, 1024, 160, 2048);
  cvt_act_kernel<<<dim3(64, 64), 256, 0, stream>>>(c_t, A1p, 2048, 160, 3072);

  // --- pack weights (transposed) ---
  cvt_wt_kernel<<<dim3(16, 64), 256, 0, stream>>>(w_if_x,   W1tp, 4096, 160, 0,    0);
  cvt_wt_kernel<<<dim3(16, 32), 256, 0, stream>>>(w_if_h,   W1tp, 4096, 160, 0,    2048);
  cvt_wt_kernel<<<dim3(16, 64), 256, 0, stream>>>(w_if_c,   W1tp, 4096, 160, 0,    3072);
  cvt_wt_kernel<<<dim3(8,  64), 256, 0, stream>>>(w_c_x,    W1tp, 2048, 160, 4096, 0);
  cvt_wt_kernel<<<dim3(8,  32), 256, 0, stream>>>(w_c_h,    W1tp, 2048, 160, 4096, 2048);
  cvt_wt_kernel<<<dim3(4,  64), 256, 0, stream>>>(w_o_x,    W1tp, 1024, 160, 6144, 0);
  cvt_wt_kernel<<<dim3(4,  32), 256, 0, stream>>>(w_o_h,    W1tp, 1024, 160, 6144, 2048);
  cvt_wt_kernel<<<dim3(4,  64), 256, 0, stream>>>(w_r_x,    W1tp, 1024, 160, 7168, 0);
  cvt_wt_kernel<<<dim3(4,  64), 256, 0, stream>>>(w_o_c,    W2tp, 1024, 128, 0,    0);
  cvt_wt_kernel<<<dim3(4,  64), 256, 0, stream>>>(w_r_proj, W2tp, 1024, 128, 1024, 2048);

  // --- stage 1: big fused GEMM -> all pre-activations ---
  gemm256_kernel<0><<<2048, 512, 0, stream>>>(A1p, W1tp, G1);

  // --- stage 2: elementwise gates -> c_new + packed A2 ---
  pass2_kernel<<<dim3(64, 64), 256, 0, stream>>>(G1, c_t, bias_i, bias_f, bias_c, c_out, A2p);

  // --- stage 3: [c_new|r_t] GEMM -> og peephole + m_t ---
  gemm256_kernel<1><<<512, 512, 0, stream>>>(A2p, W2tp, G2);

  // --- stage 4: h_new ---
  pass3_kernel<<<8192, 256, 0, stream>>>(G1, G2, bias_o, h_out);
}

// Round 9
// 1569.410 us; speedup vs baseline: 1.2427x; 1.0980x over previous
//
#include <hip/hip_runtime.h>
#include <hip/hip_bf16.h>
#include <math.h>

typedef unsigned short u16;
typedef __bf16 bf16x8_t __attribute__((ext_vector_type(8)));
typedef float  f32x8_t  __attribute__((ext_vector_type(8)));
typedef float  f32x16_t __attribute__((ext_vector_type(16)));
typedef u16    u16x4_t  __attribute__((ext_vector_type(4)));
typedef u16    u16x8_t  __attribute__((ext_vector_type(8)));

// ---------- helpers ----------
__device__ __forceinline__ u16 f2b(float f) {
  unsigned u = __builtin_bit_cast(unsigned, f);
  u += 0x7fffu + ((u >> 16) & 1u);      // RNE; inputs are finite
  return (u16)(u >> 16);
}
__device__ __forceinline__ float b2f(u16 h) {
  unsigned u = ((unsigned)h) << 16;
  return __builtin_bit_cast(float, u);
}
__device__ __forceinline__ float sigm_(float x) { return 1.0f / (1.0f + __expf(-x)); }
__device__ __forceinline__ float tanh_(float x) { return 1.0f - 2.0f / (__expf(2.0f * x) + 1.0f); }

__device__ __forceinline__ void gload16(const void* g, void* l) {
  __builtin_amdgcn_global_load_lds(
      (__attribute__((address_space(1))) void*)(g),
      (__attribute__((address_space(3))) void*)(l), 16, 0, 0);
}

// ==========================================================================
// Packed panel format (256-row tiles): [k-plane p=0..3][row 0..255][8 u16]
// = 8192 u16 (16 KB) per 256x32 tile; panel = [blk][kt][8192], stride KT.
// Staging = contiguous 16B/thread wave loads; LDS image == packed tile ->
// conflict-free ds_read_b128 fragments.
// ==========================================================================

// ---------- fused activation pack: x|h|c -> A1p (KT=160; x 0..63, h 64..95, c 96..159) ----------
__global__ void pack_act_kernel(const float* __restrict__ x, const float* __restrict__ h,
                                const float* __restrict__ c, u16* __restrict__ A1p) {
  int mb = blockIdx.x, kt = blockIdx.y, t = threadIdx.x;
  const float* src; int C, ccol;
  if (kt < 64)      { src = x; C = 2048; ccol = kt * 32; }
  else if (kt < 96) { src = h; C = 1024; ccol = (kt - 64) * 32; }
  else              { src = c; C = 2048; ccol = (kt - 96) * 32; }
  const float* s = src + (long)(mb * 256 + t) * C + ccol;
  u16* d = A1p + ((long)(mb * 160 + kt)) * 8192 + t * 8;
#pragma unroll
  for (int p = 0; p < 4; ++p) {
    f32x8_t v = *(const f32x8_t*)(s + p * 8);
    u16x8_t o;
#pragma unroll
    for (int r = 0; r < 8; ++r) o[r] = f2b(v[r]);
    *(u16x8_t*)(d + p * 2048) = o;
  }
}

// ---------- fused W1 pack (transposed) -> W1tp[32nb][160kt][8192] ----------
// col map: n 0..4095 = if-gates, 4096..6143 = c-gate, 6144..7167 = o-gate(xh), 7168..8191 = r_x
// k map: 0..63 = x-K, 64..95 = h-K, 96..159 = c-K (if-gates only)
__global__ void pack_w1_kernel(const float* __restrict__ w_if_x, const float* __restrict__ w_if_h,
                               const float* __restrict__ w_if_c, const float* __restrict__ w_c_x,
                               const float* __restrict__ w_c_h,  const float* __restrict__ w_o_x,
                               const float* __restrict__ w_o_h,  const float* __restrict__ w_r_x,
                               u16* __restrict__ W1tp) {
  int nb = blockIdx.x, kt = blockIdx.y, t = threadIdx.x;
  int n0g = nb * 256;
  const float* src; int N, nl, kl;
  if (n0g < 4096) {
    N = 4096; nl = n0g;
    if (kt < 64)      { src = w_if_x; kl = kt * 32; }
    else if (kt < 96) { src = w_if_h; kl = (kt - 64) * 32; }
    else              { src = w_if_c; kl = (kt - 96) * 32; }
  } else if (n0g < 6144) {
    N = 2048; nl = n0g - 4096;
    if (kt < 64)      { src = w_c_x; kl = kt * 32; }
    else if (kt < 96) { src = w_c_h; kl = (kt - 64) * 32; }
    else return;
  } else if (n0g < 7168) {
    N = 1024; nl = n0g - 6144;
    if (kt < 64)      { src = w_o_x; kl = kt * 32; }
    else if (kt < 96) { src = w_o_h; kl = (kt - 64) * 32; }
    else return;
  } else {
    N = 1024; nl = n0g - 7168;
    if (kt < 64)      { src = w_r_x; kl = kt * 32; }
    else return;
  }
  int n = nl + t;
  float tmp[32];
#pragma unroll
  for (int kk = 0; kk < 32; ++kk)
    tmp[kk] = src[(long)(kl + kk) * N + n];
  u16* d = W1tp + ((long)(nb * 160 + kt)) * 8192 + t * 8;
#pragma unroll
  for (int p = 0; p < 4; ++p) {
    u16x8_t o;
#pragma unroll
    for (int r = 0; r < 8; ++r) o[r] = f2b(tmp[p * 8 + r]);
    *(u16x8_t*)(d + p * 2048) = o;
  }
}

// ---------- fused W2 pack -> W2tp[8nb][128kt][8192] ----------
// nb 0..3 = w_o_c (kt 0..63), nb 4..7 = w_r_proj (kt 64..127); N = 1024 both
__global__ void pack_w2_kernel(const float* __restrict__ w_o_c,
                               const float* __restrict__ w_r_proj, u16* __restrict__ W2tp) {
  int nb = blockIdx.x, kt = blockIdx.y, t = threadIdx.x;
  const float* src; int nl, kl;
  if (nb < 4) { if (kt >= 64) return; src = w_o_c;    nl = nb * 256;       kl = kt * 32; }
  else        { if (kt < 64)  return; src = w_r_proj; nl = (nb - 4) * 256; kl = (kt - 64) * 32; }
  int n = nl + t;
  float tmp[32];
#pragma unroll
  for (int kk = 0; kk < 32; ++kk)
    tmp[kk] = src[(long)(kl + kk) * 1024 + n];
  u16* d = W2tp + ((long)(nb * 128 + kt)) * 8192 + t * 8;
#pragma unroll
  for (int p = 0; p < 4; ++p) {
    u16x8_t o;
#pragma unroll
    for (int r = 0; r < 8; ++r) o[r] = f2b(tmp[p * 8 + r]);
    *(u16x8_t*)(d + p * 2048) = o;
  }
}

// ==========================================================================
// 256x256 bf16 GEMM — R4 pipeline (BK=32, 3-slot ring, stage t+2, vmcnt(4)
// edge, 1 barrier/tile, compiler-counted lgkm, setprio) with 32x32x16 MFMA
// (20% better FLOP/cyc than 16x16x32: 8.07 cyc / 32k FLOP, m119).
// 8 waves (2M x 4N), wave tile 128x64, acc[4][2] f32x16 (AGPR).
// Frags: A rows wr*128+mm*32+l31, B rows wc*64+nn*32+l31, plane (2ks+hl).
// Operands swapped (W as MFMA A-op): out row = l31 (+mm*32),
// cols = nn*32 + g*8 + 4*hl + r   [verified R6/R7/R8].
// MODE 0: A1p[64mb x 160kt] x W1tp[32nb x 160kt] -> G1 [16384,8192]
//         NT per nb: nb<16 -> 160, nb<28 -> 96, else 64 (segmented K)
// MODE 1: A2p[64mb x 128kt] x W2tp[8nb x 128kt]  -> G2 [16384,2048], NT=64
// ==========================================================================
template <int MODE>
__global__ __launch_bounds__(512, 2) void gemm256_kernel(
    const u16* __restrict__ A, const u16* __restrict__ Bt, u16* __restrict__ Cout) {
  constexpr int KTF  = (MODE == 0) ? 160 : 128;
  constexpr int NCOL = (MODE == 0) ? 8192 : 2048;
  constexpr int NBN  = NCOL / 256;
  constexpr int SLOT = 16384;   // u16 per ring slot (A 8192 + B 8192)

  __shared__ u16 lds[3 * SLOT];  // 96 KiB

  // XCD-bijective swizzle (grid % 8 == 0 in both modes)
  int bid = blockIdx.x;
  int cpx = gridDim.x >> 3;
  bid = (bid & 7) * cpx + (bid >> 3);

  int mb = bid / NBN, nb = bid % NBN;
  int m0 = mb * 256, n0 = nb * 256;

  int kt0, NT;  // K32-tile units
  if (MODE == 0) { kt0 = 0; NT = (nb < 16) ? 160 : ((nb < 28) ? 96 : 64); }
  else           { kt0 = (nb < 4) ? 0 : 64; NT = 64; }

  const int tid  = threadIdx.x;
  const int lane = tid & 63;
  const int wid  = tid >> 6;
  const int wr   = wid >> 2;       // 0..1  (wave row: 128 output rows)
  const int wc   = wid & 3;        // 0..3  (wave col: 64 output cols)
  const int l31  = lane & 31;
  const int hl   = lane >> 5;

  // staging: thread copies 2x16B of A + 2x16B of B per tile (4 gloads)
  const int dstg = tid * 8;  // u16
  const u16* pA = A  + ((long)(mb * KTF + kt0)) * 8192 + dstg;
  const u16* pB = Bt + ((long)(nb * KTF + kt0)) * 8192 + dstg;

#define STAGE(t, s) do { \
    gload16(pA + (long)(t) * 8192,        &lds[(s) * SLOT + dstg]); \
    gload16(pA + (long)(t) * 8192 + 4096, &lds[(s) * SLOT + dstg + 4096]); \
    gload16(pB + (long)(t) * 8192,        &lds[(s) * SLOT + 8192 + dstg]); \
    gload16(pB + (long)(t) * 8192 + 4096, &lds[(s) * SLOT + 8192 + dstg + 4096]); } while (0)

  // fragment bases (u16 units): plane term (2*ks+hl)*2048 added per slice
  const int abase = (wr * 128 + l31) * 8;  // + mm*256
  const int bbase = (wc * 64  + l31) * 8;  // + nn*256

  f32x16_t acc[4][2];
#pragma unroll
  for (int m = 0; m < 4; ++m)
#pragma unroll
    for (int n = 0; n < 2; ++n)
#pragma unroll
      for (int r = 0; r < 16; ++r) acc[m][n][r] = 0.f;

  // prologue: stage tiles 0,1
  STAGE(0, 0); STAGE(1, 1);
  asm volatile("s_waitcnt vmcnt(4)" ::: "memory");   // tile 0 resident
  __builtin_amdgcn_s_barrier();

  int slot = 0, s2 = 2;
  for (int t = 0; t < NT; ++t) {
    const u16* sA = &lds[slot * SLOT];
    const u16* sB = sA + 8192;
    const bool pre = (t + 2 < NT);
    if (pre) STAGE(t + 2, s2);

    bf16x8_t xa[4], xb[4], wa[2], wb[2];
#pragma unroll
    for (int m = 0; m < 4; ++m) {
      xa[m] = *(const bf16x8_t*)&sA[hl * 2048 + abase + m * 256];
      xb[m] = *(const bf16x8_t*)&sA[(2 + hl) * 2048 + abase + m * 256];
    }
#pragma unroll
    for (int n = 0; n < 2; ++n) {
      wa[n] = *(const bf16x8_t*)&sB[hl * 2048 + bbase + n * 256];
      wb[n] = *(const bf16x8_t*)&sB[(2 + hl) * 2048 + bbase + n * 256];
    }

    __builtin_amdgcn_s_setprio(1);
#pragma unroll
    for (int m = 0; m < 4; ++m)
#pragma unroll
      for (int n = 0; n < 2; ++n)
        acc[m][n] = __builtin_amdgcn_mfma_f32_32x32x16_bf16(wa[n], xa[m], acc[m][n], 0, 0, 0);
#pragma unroll
    for (int m = 0; m < 4; ++m)
#pragma unroll
      for (int n = 0; n < 2; ++n)
        acc[m][n] = __builtin_amdgcn_mfma_f32_32x32x16_bf16(wb[n], xb[m], acc[m][n], 0, 0, 0);
    __builtin_amdgcn_s_setprio(0);

    if (pre) asm volatile("s_waitcnt vmcnt(4)" ::: "memory");  // t+1 resident, t+2 in flight
    else     asm volatile("s_waitcnt vmcnt(0)" ::: "memory");  // epilogue drain
    __builtin_amdgcn_s_barrier();

    slot = (slot == 2) ? 0 : slot + 1;
    s2   = (s2   == 2) ? 0 : s2   + 1;
  }
#undef STAGE

  // epilogue: row = l31 (+mm*32), cols = nn*32 + g*8 + 4*hl + 0..3
  const long rowg = (long)(m0 + wr * 128 + l31);
  const int  colg = n0 + wc * 64 + 4 * hl;
#pragma unroll
  for (int mm = 0; mm < 4; ++mm) {
    long rb = (rowg + mm * 32) * (long)NCOL;
#pragma unroll
    for (int nn = 0; nn < 2; ++nn) {
#pragma unroll
      for (int g = 0; g < 4; ++g) {
        u16x4_t o;
#pragma unroll
        for (int r = 0; r < 4; ++r) o[r] = f2b(acc[mm][nn][g * 4 + r]);
        *(u16x4_t*)&Cout[rb + colg + nn * 32 + g * 8] = o;
      }
    }
  }
}

// ---------- pass2: gates -> c_new (fp32), A2 packed = [bf16(c_new) | bf16(tanh(c_new))] ----------
__global__ void pass2_kernel(const u16* __restrict__ G1, const float* __restrict__ c_t,
                             const float* __restrict__ bias_i, const float* __restrict__ bias_f,
                             const float* __restrict__ bias_c,
                             float* __restrict__ c_new_out, u16* __restrict__ A2p) {
  int mb = blockIdx.x, jg = blockIdx.y, t = threadIdx.x;
  int b = mb * 256 + t;
  int j0 = jg * 32;
  const u16* row = G1 + (long)b * 8192 + j0;
  const float* cp_p = c_t + (long)b * 2048 + j0;
  float* co_p = c_new_out + (long)b * 2048 + j0;
  u16* dc = A2p + ((long)(mb * 128 + jg)) * 8192 + t * 8;
  u16* dr = dc + (long)64 * 8192;

#pragma unroll
  for (int q = 0; q < 4; ++q) {
    u16x8_t ip = *(const u16x8_t*)(row + q * 8);
    u16x8_t fp = *(const u16x8_t*)(row + 2048 + q * 8);
    u16x8_t gp = *(const u16x8_t*)(row + 4096 + q * 8);
    f32x8_t cp = *(const f32x8_t*)(cp_p + q * 8);
    f32x8_t bi = *(const f32x8_t*)(bias_i + j0 + q * 8);
    f32x8_t bf = *(const f32x8_t*)(bias_f + j0 + q * 8);
    f32x8_t bc = *(const f32x8_t*)(bias_c + j0 + q * 8);
    f32x8_t cn;
    u16x8_t cb, rb;
#pragma unroll
    for (int r = 0; r < 8; ++r) {
      float ig = sigm_(b2f(ip[r]) + bi[r]);
      float fg = sigm_(b2f(fp[r]) + bf[r]);
      float g  = tanh_(b2f(gp[r]) + bc[r]);
      float c  = fg * cp[r] + ig * g;
      cn[r] = c;
      cb[r] = f2b(c);
      rb[r] = f2b(tanh_(c));
    }
    *(f32x8_t*)(co_p + q * 8) = cn;
    *(u16x8_t*)(dc + q * 2048) = cb;
    *(u16x8_t*)(dr + q * 2048) = rb;
  }
}

// ---------- pass3: h_new = sigmoid(og_pre + c@Woc + bias_o) * (m_t + xr) ----------
__global__ void pass3_kernel(const u16* __restrict__ G1, const u16* __restrict__ G2,
                             const float* __restrict__ bias_o, float* __restrict__ h_out) {
  long i = (long)blockIdx.x * blockDim.x + threadIdx.x;
  long e = i * 8;
  int b = (int)(e >> 10);
  int j = (int)(e & 1023);
  const u16* row1 = G1 + (long)b * 8192;
  const u16* row2 = G2 + (long)b * 2048;
  u16x8_t ogp = *(const u16x8_t*)(row1 + 6144 + j);
  u16x8_t xrp = *(const u16x8_t*)(row1 + 7168 + j);
  u16x8_t ocg = *(const u16x8_t*)(row2 + j);
  u16x8_t mt  = *(const u16x8_t*)(row2 + 1024 + j);
  f32x8_t bo  = *(const f32x8_t*)(bias_o + j);
  f32x8_t h;
#pragma unroll
  for (int r = 0; r < 8; ++r) {
    float og = sigm_(b2f(ogp[r]) + b2f(ocg[r]) + bo[r]);
    h[r] = og * (b2f(mt[r]) + b2f(xrp[r]));
  }
  *(f32x8_t*)(h_out + (long)b * 1024 + j) = h;
}

// ---------- launch ----------
extern "C" void kernel_launch(void* const* d_in, const int* in_sizes, int n_in,
                              void* d_out, int out_size, void* d_ws, size_t ws_size,
                              hipStream_t stream) {
  const float* x_t      = (const float*)d_in[0];
  const float* h_t      = (const float*)d_in[1];
  const float* c_t      = (const float*)d_in[2];
  const float* w_if_x   = (const float*)d_in[3];
  const float* w_if_h   = (const float*)d_in[4];
  const float* w_if_c   = (const float*)d_in[5];
  const float* bias_i   = (const float*)d_in[6];
  const float* bias_f   = (const float*)d_in[7];
  const float* w_c_x    = (const float*)d_in[8];
  const float* w_c_h    = (const float*)d_in[9];
  const float* bias_c   = (const float*)d_in[10];
  const float* w_o_x    = (const float*)d_in[11];
  const float* w_o_h    = (const float*)d_in[12];
  const float* w_o_c    = (const float*)d_in[13];
  const float* bias_o   = (const float*)d_in[14];
  const float* w_r_proj = (const float*)d_in[15];
  const float* w_r_x    = (const float*)d_in[16];

  char* ws = (char*)d_ws;
  u16* A1p  = (u16*)(ws);
  u16* W1tp = (u16*)(ws + 167772160L);
  u16* G1   = (u16*)(ws + 251658240L);
  u16* W2tp = (u16*)(ws + 520093696L);
  u16* A2p  = (u16*)(ws);               // aliases A1p (dead after GEMM1)
  u16* G2   = (u16*)(ws + 167772160L);  // aliases W1tp (dead after GEMM1)

  float* h_out = (float*)d_out;
  float* c_out = h_out + 16384L * 1024L;

  // --- stage 0: fused packing (3 launches) ---
  pack_act_kernel<<<dim3(64, 160), 256, 0, stream>>>(x_t, h_t, c_t, A1p);
  pack_w1_kernel<<<dim3(32, 160), 256, 0, stream>>>(w_if_x, w_if_h, w_if_c, w_c_x, w_c_h,
                                                    w_o_x, w_o_h, w_r_x, W1tp);
  pack_w2_kernel<<<dim3(8, 128), 256, 0, stream>>>(w_o_c, w_r_proj, W2tp);

  // --- stage 1: big fused GEMM -> all pre-activations ---
  gemm256_kernel<0><<<2048, 512, 0, stream>>>(A1p, W1tp, G1);

  // --- stage 2: elementwise gates -> c_new + packed A2 ---
  pass2_kernel<<<dim3(64, 64), 256, 0, stream>>>(G1, c_t, bias_i, bias_f, bias_c, c_out, A2p);

  // --- stage 3: [c_new|r_t] GEMM -> og peephole + m_t ---
  gemm256_kernel<1><<<512, 512, 0, stream>>>(A2p, W2tp, G2);

  // --- stage 4: h_new ---
  pass3_kernel<<<8192, 256, 0, stream>>>(G1, G2, bias_o, h_out);
}

// Round 10
// 1492.487 us; speedup vs baseline: 1.3068x; 1.0515x over previous
//
#include <hip/hip_runtime.h>
#include <hip/hip_bf16.h>
#include <math.h>

typedef unsigned short u16;
typedef __bf16 bf16x8_t __attribute__((ext_vector_type(8)));
typedef float  f32x4_t  __attribute__((ext_vector_type(4)));
typedef float  f32x8_t  __attribute__((ext_vector_type(8)));
typedef u16    u16x4_t  __attribute__((ext_vector_type(4)));
typedef u16    u16x8_t  __attribute__((ext_vector_type(8)));

// ---------- helpers ----------
__device__ __forceinline__ u16 f2b(float f) {
  unsigned u = __builtin_bit_cast(unsigned, f);
  u += 0x7fffu + ((u >> 16) & 1u);      // RNE; inputs are finite
  return (u16)(u >> 16);
}
__device__ __forceinline__ float b2f(u16 h) {
  unsigned u = ((unsigned)h) << 16;
  return __builtin_bit_cast(float, u);
}
__device__ __forceinline__ float sigm_(float x) { return 1.0f / (1.0f + __expf(-x)); }
__device__ __forceinline__ float tanh_(float x) { return 1.0f - 2.0f / (__expf(2.0f * x) + 1.0f); }

__device__ __forceinline__ void gload16(const void* g, void* l) {
  __builtin_amdgcn_global_load_lds(
      (__attribute__((address_space(1))) void*)(g),
      (__attribute__((address_space(3))) void*)(l), 16, 0, 0);
}

// ==========================================================================
// Packed panel formats (k-plane = 8 consecutive k as 16B per row):
//  256-row tiles: [p 0..3][row 0..255][8 u16] = 8192 u16 (16 KB)
//  128-row tiles: [p 0..3][row 0..127][8 u16] = 4096 u16 ( 8 KB)
// Staging = contiguous 16B/thread wave loads; LDS image == packed tile ->
// conflict-free ds_read_b128 fragments.
// ==========================================================================

// ---------- fused activation pack: x|h|c -> A1p (KT=160; x 0..63, h 64..95, c 96..159) ----------
__global__ void pack_act_kernel(const float* __restrict__ x, const float* __restrict__ h,
                                const float* __restrict__ c, u16* __restrict__ A1p) {
  int mb = blockIdx.x, kt = blockIdx.y, t = threadIdx.x;
  const float* src; int C, ccol;
  if (kt < 64)      { src = x; C = 2048; ccol = kt * 32; }
  else if (kt < 96) { src = h; C = 1024; ccol = (kt - 64) * 32; }
  else              { src = c; C = 2048; ccol = (kt - 96) * 32; }
  const float* s = src + (long)(mb * 256 + t) * C + ccol;
  u16* d = A1p + ((long)(mb * 160 + kt)) * 8192 + t * 8;
#pragma unroll
  for (int p = 0; p < 4; ++p) {
    f32x8_t v = *(const f32x8_t*)(s + p * 8);
    u16x8_t o;
#pragma unroll
    for (int r = 0; r < 8; ++r) o[r] = f2b(v[r]);
    *(u16x8_t*)(d + p * 2048) = o;
  }
}

// ---------- fused W1 pack (transposed) -> W1tp[32nb][160kt][8192] ----------
__global__ void pack_w1_kernel(const float* __restrict__ w_if_x, const float* __restrict__ w_if_h,
                               const float* __restrict__ w_if_c, const float* __restrict__ w_c_x,
                               const float* __restrict__ w_c_h,  const float* __restrict__ w_o_x,
                               const float* __restrict__ w_o_h,  const float* __restrict__ w_r_x,
                               u16* __restrict__ W1tp) {
  int nb = blockIdx.x, kt = blockIdx.y, t = threadIdx.x;
  int n0g = nb * 256;
  const float* src; int N, nl, kl;
  if (n0g < 4096) {
    N = 4096; nl = n0g;
    if (kt < 64)      { src = w_if_x; kl = kt * 32; }
    else if (kt < 96) { src = w_if_h; kl = (kt - 64) * 32; }
    else              { src = w_if_c; kl = (kt - 96) * 32; }
  } else if (n0g < 6144) {
    N = 2048; nl = n0g - 4096;
    if (kt < 64)      { src = w_c_x; kl = kt * 32; }
    else if (kt < 96) { src = w_c_h; kl = (kt - 64) * 32; }
    else return;
  } else if (n0g < 7168) {
    N = 1024; nl = n0g - 6144;
    if (kt < 64)      { src = w_o_x; kl = kt * 32; }
    else if (kt < 96) { src = w_o_h; kl = (kt - 64) * 32; }
    else return;
  } else {
    N = 1024; nl = n0g - 7168;
    if (kt < 64)      { src = w_r_x; kl = kt * 32; }
    else return;
  }
  int n = nl + t;
  float tmp[32];
#pragma unroll
  for (int kk = 0; kk < 32; ++kk)
    tmp[kk] = src[(long)(kl + kk) * N + n];
  u16* d = W1tp + ((long)(nb * 160 + kt)) * 8192 + t * 8;
#pragma unroll
  for (int p = 0; p < 4; ++p) {
    u16x8_t o;
#pragma unroll
    for (int r = 0; r < 8; ++r) o[r] = f2b(tmp[p * 8 + r]);
    *(u16x8_t*)(d + p * 2048) = o;
  }
}

// ---------- W2 pack -> W2q[8cg][128kt][4096] (128-row tiles) ----------
// kt<64: w_o_c (K = kt*32..), kt>=64: w_r_proj; cols n = cg*128 + t
__global__ void pack_w2_kernel(const float* __restrict__ w_o_c,
                               const float* __restrict__ w_r_proj, u16* __restrict__ W2q) {
  int cg = blockIdx.x, kt = blockIdx.y, t = threadIdx.x;   // block = 128 threads
  const float* src; int kl;
  if (kt < 64) { src = w_o_c;    kl = kt * 32; }
  else         { src = w_r_proj; kl = (kt - 64) * 32; }
  int n = cg * 128 + t;
  float tmp[32];
#pragma unroll
  for (int kk = 0; kk < 32; ++kk)
    tmp[kk] = src[(long)(kl + kk) * 1024 + n];
  u16* d = W2q + ((long)(cg * 128 + kt)) * 4096 + t * 8;
#pragma unroll
  for (int p = 0; p < 4; ++p) {
    u16x8_t o;
#pragma unroll
    for (int r = 0; r < 8; ++r) o[r] = f2b(tmp[p * 8 + r]);
    *(u16x8_t*)(d + p * 1024) = o;
  }
}

// ==========================================================================
// GEMM1: R4-exact 256x256 bf16, 16x16x32 MFMA, 8 waves (2M x 4N), BK=32,
// 3-slot LDS ring (96KB), stage t+2, boundary vmcnt(4), 1 barrier/tile.
// Operands swapped (W as A-op): out row = lane&15 (+...), cols 4-grouped.
// A1p[64mb x 160kt] x W1tp[32nb x 160kt] -> G1 [16384,8192]
// NT per nb: nb<16 -> 160, nb<28 -> 96, else 64 (segmented K).  [986us @ R4]
// ==========================================================================
__global__ __launch_bounds__(512, 2) void gemm1_kernel(
    const u16* __restrict__ A, const u16* __restrict__ Bt, u16* __restrict__ Cout) {
  constexpr int KTF  = 160;
  constexpr int NCOL = 8192;
  constexpr int NBN  = 32;
  constexpr int SLOT = 16384;   // u16 per ring slot (A 8192 + B 8192)

  __shared__ u16 lds[3 * SLOT];  // 96 KiB

  int bid = blockIdx.x;
  int cpx = gridDim.x >> 3;
  bid = (bid & 7) * cpx + (bid >> 3);

  int mb = bid / NBN, nb = bid % NBN;
  int m0 = mb * 256, n0 = nb * 256;

  int NT = (nb < 16) ? 160 : ((nb < 28) ? 96 : 64);

  const int tid  = threadIdx.x;
  const int lane = tid & 63;
  const int wid  = tid >> 6;
  const int wr   = wid >> 2;       // 0..1
  const int wc   = wid & 3;        // 0..3
  const int hl16 = lane >> 4;      // 0..3 (k-plane)
  const int l15  = lane & 15;

  const int dstg = tid * 8;  // u16
  const u16* pA = A  + ((long)(mb * KTF)) * 8192 + dstg;
  const u16* pB = Bt + ((long)(nb * KTF)) * 8192 + dstg;

#define STAGE(t, s) do { \
    gload16(pA + (long)(t) * 8192,        &lds[(s) * SLOT + dstg]); \
    gload16(pA + (long)(t) * 8192 + 4096, &lds[(s) * SLOT + dstg + 4096]); \
    gload16(pB + (long)(t) * 8192,        &lds[(s) * SLOT + 8192 + dstg]); \
    gload16(pB + (long)(t) * 8192 + 4096, &lds[(s) * SLOT + 8192 + dstg + 4096]); } while (0)

  const int aoff = hl16 * 2048 + (wr * 128 + l15) * 8;  // + m*128 (16 rows)
  const int boff = hl16 * 2048 + (wc * 64  + l15) * 8;  // + n*128

  f32x4_t acc[8][4];
#pragma unroll
  for (int m = 0; m < 8; ++m)
#pragma unroll
    for (int n = 0; n < 4; ++n) acc[m][n] = (f32x4_t){0.f, 0.f, 0.f, 0.f};

  STAGE(0, 0); STAGE(1, 1);
  asm volatile("s_waitcnt vmcnt(4)" ::: "memory");
  __builtin_amdgcn_s_barrier();

  int slot = 0, s2 = 2;
  for (int t = 0; t < NT; ++t) {
    const u16* sA = &lds[slot * SLOT];
    const u16* sB = sA + 8192;
    const bool pre = (t + 2 < NT);
    if (pre) STAGE(t + 2, s2);

    bf16x8_t bv[4], av[8];
#pragma unroll
    for (int n = 0; n < 4; ++n) bv[n] = *(const bf16x8_t*)&sB[boff + n * 128];
#pragma unroll
    for (int m = 0; m < 8; ++m) av[m] = *(const bf16x8_t*)&sA[aoff + m * 128];

    __builtin_amdgcn_s_setprio(1);
#pragma unroll
    for (int m = 0; m < 8; ++m)
#pragma unroll
      for (int n = 0; n < 4; ++n)
        acc[m][n] = __builtin_amdgcn_mfma_f32_16x16x32_bf16(bv[n], av[m], acc[m][n], 0, 0, 0);
    __builtin_amdgcn_s_setprio(0);

    if (pre) asm volatile("s_waitcnt vmcnt(4)" ::: "memory");
    else     asm volatile("s_waitcnt vmcnt(0)" ::: "memory");
    __builtin_amdgcn_s_barrier();

    slot = (slot == 2) ? 0 : slot + 1;
    s2   = (s2   == 2) ? 0 : s2   + 1;
  }
#undef STAGE

  const int rowm = lane & 15;
  const int col4 = (lane >> 4) * 4;
#pragma unroll
  for (int m = 0; m < 8; ++m) {
    long rg = (long)(m0 + wr * 128 + m * 16 + rowm) * NCOL;
#pragma unroll
    for (int n = 0; n < 4; ++n) {
      int cg = n0 + wc * 64 + n * 16 + col4;
      u16x4_t o;
#pragma unroll
      for (int r = 0; r < 4; ++r) o[r] = f2b(acc[m][n][r]);
      *(u16x4_t*)&Cout[rg + cg] = o;
    }
  }
}

// ---------- pass2: gates -> c_new (fp32), A2 packed = [bf16(c_new) | bf16(tanh(c_new))] ----------
__global__ void pass2_kernel(const u16* __restrict__ G1, const float* __restrict__ c_t,
                             const float* __restrict__ bias_i, const float* __restrict__ bias_f,
                             const float* __restrict__ bias_c,
                             float* __restrict__ c_new_out, u16* __restrict__ A2p) {
  int mb = blockIdx.x, jg = blockIdx.y, t = threadIdx.x;
  int b = mb * 256 + t;
  int j0 = jg * 32;
  const u16* row = G1 + (long)b * 8192 + j0;
  const float* cp_p = c_t + (long)b * 2048 + j0;
  float* co_p = c_new_out + (long)b * 2048 + j0;
  u16* dc = A2p + ((long)(mb * 128 + jg)) * 8192 + t * 8;
  u16* dr = dc + (long)64 * 8192;

#pragma unroll
  for (int q = 0; q < 4; ++q) {
    u16x8_t ip = *(const u16x8_t*)(row + q * 8);
    u16x8_t fp = *(const u16x8_t*)(row + 2048 + q * 8);
    u16x8_t gp = *(const u16x8_t*)(row + 4096 + q * 8);
    f32x8_t cp = *(const f32x8_t*)(cp_p + q * 8);
    f32x8_t bi = *(const f32x8_t*)(bias_i + j0 + q * 8);
    f32x8_t bf = *(const f32x8_t*)(bias_f + j0 + q * 8);
    f32x8_t bc = *(const f32x8_t*)(bias_c + j0 + q * 8);
    f32x8_t cn;
    u16x8_t cb, rb;
#pragma unroll
    for (int r = 0; r < 8; ++r) {
      float ig = sigm_(b2f(ip[r]) + bi[r]);
      float fg = sigm_(b2f(fp[r]) + bf[r]);
      float g  = tanh_(b2f(gp[r]) + bc[r]);
      float c  = fg * cp[r] + ig * g;
      cn[r] = c;
      cb[r] = f2b(c);
      rb[r] = f2b(tanh_(c));
    }
    *(f32x8_t*)(co_p + q * 8) = cn;
    *(u16x8_t*)(dc + q * 2048) = cb;
    *(u16x8_t*)(dr + q * 2048) = rb;
  }
}

// ==========================================================================
// gemm2h: fused GEMM2 + h-epilogue. 256 rows x 128 cols per block; each
// block computes BOTH ocg = c_new@W_o_c (kt 0..63) and mt = r_t@W_r_proj
// (kt 64..127) for the SAME columns via dual accumulators, then
// h = sigmoid(og_pre + ocg + bias_o) * (mt + xr) in-register (fp32 ocg/mt).
// 8 waves (4M x 2N), wave tile 64x64 per output; acc[2][4][4] f32x4.
// LDS 3 x (A 16KB + B 8KB) = 72 KB; stage t+2, boundary vmcnt(3).
// Eliminates G2 buffer and pass3 kernel entirely.
// ==========================================================================
__global__ __launch_bounds__(512, 2) void gemm2h_kernel(
    const u16* __restrict__ A2p, const u16* __restrict__ W2q,
    const u16* __restrict__ G1, const float* __restrict__ bias_o,
    float* __restrict__ h_out) {
  constexpr int SLOT = 12288;  // u16: A 8192 + B 4096

  __shared__ u16 lds[3 * SLOT];  // 72 KiB

  int bid = blockIdx.x;          // grid = 512
  int cpx = gridDim.x >> 3;
  bid = (bid & 7) * cpx + (bid >> 3);

  int mb = bid >> 3, cg = bid & 7;
  int m0 = mb * 256, c0 = cg * 128;

  const int tid  = threadIdx.x;
  const int lane = tid & 63;
  const int wid  = tid >> 6;
  const int wr   = wid >> 1;     // 0..3 (64-row band)
  const int wc   = wid & 1;      // 0..1 (64-col band)
  const int hl16 = lane >> 4;
  const int l15  = lane & 15;

  const int dstg = tid * 8;  // u16, < 4096
  const u16* pA = A2p + ((long)(mb * 128)) * 8192 + dstg;
  const u16* pB = W2q + ((long)(cg * 128)) * 4096 + dstg;

#define STAGE2(t, s) do { \
    gload16(pA + (long)(t) * 8192,        &lds[(s) * SLOT + dstg]); \
    gload16(pA + (long)(t) * 8192 + 4096, &lds[(s) * SLOT + dstg + 4096]); \
    gload16(pB + (long)(t) * 4096,        &lds[(s) * SLOT + 8192 + dstg]); } while (0)

  const int aoff = hl16 * 2048 + (wr * 64 + l15) * 8;  // + m*128
  const int boff = hl16 * 1024 + (wc * 64 + l15) * 8;  // + n*128

  f32x4_t acc0[4][4], acc1[4][4];
#pragma unroll
  for (int m = 0; m < 4; ++m)
#pragma unroll
    for (int n = 0; n < 4; ++n) {
      acc0[m][n] = (f32x4_t){0.f, 0.f, 0.f, 0.f};
      acc1[m][n] = (f32x4_t){0.f, 0.f, 0.f, 0.f};
    }

  STAGE2(0, 0); STAGE2(1, 1);
  asm volatile("s_waitcnt vmcnt(3)" ::: "memory");
  __builtin_amdgcn_s_barrier();

  int slot = 0, s2 = 2;
  for (int t = 0; t < 128; ++t) {
    const u16* sA = &lds[slot * SLOT];
    const u16* sB = sA + 8192;
    const bool pre = (t + 2 < 128);
    if (pre) STAGE2(t + 2, s2);

    bf16x8_t wv[4], av[4];
#pragma unroll
    for (int n = 0; n < 4; ++n) wv[n] = *(const bf16x8_t*)&sB[boff + n * 128];
#pragma unroll
    for (int m = 0; m < 4; ++m) av[m] = *(const bf16x8_t*)&sA[aoff + m * 128];

    __builtin_amdgcn_s_setprio(1);
    if (t < 64) {
#pragma unroll
      for (int m = 0; m < 4; ++m)
#pragma unroll
        for (int n = 0; n < 4; ++n)
          acc0[m][n] = __builtin_amdgcn_mfma_f32_16x16x32_bf16(wv[n], av[m], acc0[m][n], 0, 0, 0);
    } else {
#pragma unroll
      for (int m = 0; m < 4; ++m)
#pragma unroll
        for (int n = 0; n < 4; ++n)
          acc1[m][n] = __builtin_amdgcn_mfma_f32_16x16x32_bf16(wv[n], av[m], acc1[m][n], 0, 0, 0);
    }
    __builtin_amdgcn_s_setprio(0);

    if (pre) asm volatile("s_waitcnt vmcnt(3)" ::: "memory");
    else     asm volatile("s_waitcnt vmcnt(0)" ::: "memory");
    __builtin_amdgcn_s_barrier();

    slot = (slot == 2) ? 0 : slot + 1;
    s2   = (s2   == 2) ? 0 : s2   + 1;
  }
#undef STAGE2

  // ---- fused h epilogue ----
  // out rows = m0 + wr*64 + m*16 + l15 ; cols j = c0 + wc*64 + n*16 + 4*hl16 + r
#pragma unroll
  for (int m = 0; m < 4; ++m) {
    int row = m0 + wr * 64 + m * 16 + l15;
    const u16* g1r = G1 + (long)row * 8192;
#pragma unroll
    for (int n = 0; n < 4; ++n) {
      int jb = c0 + wc * 64 + n * 16 + 4 * hl16;
      u16x4_t og = *(const u16x4_t*)(g1r + 6144 + jb);
      u16x4_t xr = *(const u16x4_t*)(g1r + 7168 + jb);
      f32x4_t bo = *(const f32x4_t*)(bias_o + jb);
      f32x4_t h;
#pragma unroll
      for (int r = 0; r < 4; ++r) {
        float ogate = sigm_(acc0[m][n][r] + b2f(og[r]) + bo[r]);
        h[r] = ogate * (acc1[m][n][r] + b2f(xr[r]));
      }
      *(f32x4_t*)&h_out[(long)row * 1024 + jb] = h;
    }
  }
}

// ---------- launch ----------
extern "C" void kernel_launch(void* const* d_in, const int* in_sizes, int n_in,
                              void* d_out, int out_size, void* d_ws, size_t ws_size,
                              hipStream_t stream) {
  const float* x_t      = (const float*)d_in[0];
  const float* h_t      = (const float*)d_in[1];
  const float* c_t      = (const float*)d_in[2];
  const float* w_if_x   = (const float*)d_in[3];
  const float* w_if_h   = (const float*)d_in[4];
  const float* w_if_c   = (const float*)d_in[5];
  const float* bias_i   = (const float*)d_in[6];
  const float* bias_f   = (const float*)d_in[7];
  const float* w_c_x    = (const float*)d_in[8];
  const float* w_c_h    = (const float*)d_in[9];
  const float* bias_c   = (const float*)d_in[10];
  const float* w_o_x    = (const float*)d_in[11];
  const float* w_o_h    = (const float*)d_in[12];
  const float* w_o_c    = (const float*)d_in[13];
  const float* bias_o   = (const float*)d_in[14];
  const float* w_r_proj = (const float*)d_in[15];
  const float* w_r_x    = (const float*)d_in[16];

  char* ws = (char*)d_ws;
  // layout:
  //   A1p  [64][160][8192]u16 @ 0        (160 MiB)
  //   W1tp [32][160][8192]u16 @ 160 MiB  ( 80 MiB)
  //   G1   [16384,8192] bf16  @ 240 MiB  (256 MiB)
  //   W2q  [8][128][4096]u16  @ 496 MiB  (  8 MiB)
  //   A2p  [64][128][8192]u16 @ 0        (aliases A1p, dead after GEMM1)
  u16* A1p  = (u16*)(ws);
  u16* W1tp = (u16*)(ws + 167772160L);
  u16* G1   = (u16*)(ws + 251658240L);
  u16* W2q  = (u16*)(ws + 520093696L);
  u16* A2p  = (u16*)(ws);

  float* h_out = (float*)d_out;
  float* c_out = h_out + 16384L * 1024L;

  // --- stage 0: fused packing ---
  pack_act_kernel<<<dim3(64, 160), 256, 0, stream>>>(x_t, h_t, c_t, A1p);
  pack_w1_kernel<<<dim3(32, 160), 256, 0, stream>>>(w_if_x, w_if_h, w_if_c, w_c_x, w_c_h,
                                                    w_o_x, w_o_h, w_r_x, W1tp);
  pack_w2_kernel<<<dim3(8, 128), 128, 0, stream>>>(w_o_c, w_r_proj, W2q);

  // --- stage 1: big fused GEMM -> all pre-activations ---
  gemm1_kernel<<<2048, 512, 0, stream>>>(A1p, W1tp, G1);

  // --- stage 2: elementwise gates -> c_new + packed A2 ---
  pass2_kernel<<<dim3(64, 64), 256, 0, stream>>>(G1, c_t, bias_i, bias_f, bias_c, c_out, A2p);

  // --- stage 3: fused [ocg|mt] GEMM + h epilogue (no G2, no pass3) ---
  gemm2h_kernel<<<512, 512, 0, stream>>>(A2p, W2q, G1, bias_o, h_out);
}